// Round 1
// baseline (1201.558 us; speedup 1.0000x reference)
//
#include <hip/hip_runtime.h>
#include <math.h>
#include <cfloat>

// ---------------- problem constants ----------------
#define G_    50
#define N0_   1000
#define NEDGE 200000
#define P_    10
#define FEAT_ 1036
#define NHID_ 128
#define GDIM_ 32
#define K0_   200          // ceil(0.2*1000)
#define K1_   40           // ceil(0.2*200)
#define K2_   8            // ceil(0.2*40)
#define M0_   (G_*N0_)     // 50000
#define M1_   (G_*K0_)     // 10000
#define M2_   (G_*K1_)     // 2000
#define M3_   (G_*K2_)     // 400

// ---------------- kernels ----------------

// max over rows of x[:, c] for c<12, via atomicMax on int bits (values >= 0)
__global__ void colmax_kernel(const float* __restrict__ x, int* __restrict__ scale_i) {
  int c = blockIdx.x;                 // 0..11
  int chunk = blockIdx.y;             // 0..31
  const int rows_per = (M0_ + gridDim.y - 1) / gridDim.y;
  int r0 = chunk * rows_per;
  int r1 = min(r0 + rows_per, M0_);
  float mx = 0.f;
  for (int r = r0 + (int)threadIdx.x; r < r1; r += blockDim.x)
    mx = fmaxf(mx, x[(size_t)r * FEAT_ + c]);
  __shared__ float red[256];
  red[threadIdx.x] = mx;
  __syncthreads();
  for (int s = 128; s > 0; s >>= 1) {
    if ((int)threadIdx.x < s) red[threadIdx.x] = fmaxf(red[threadIdx.x], red[threadIdx.x + s]);
    __syncthreads();
  }
  if (threadIdx.x == 0) atomicMax(scale_i + c, __float_as_int(red[0]));
}

// W01[j, 0:128] = wl[j,:]*s(j), W01[j,128:256] = wr[j,:]*s(j);  s(j)=1/colmax[j] for j<12
__global__ void scale_w01_kernel(const float* __restrict__ wl, const float* __restrict__ wr,
                                 const int* __restrict__ scale_i, float* __restrict__ W) {
  int idx = blockIdx.x * blockDim.x + threadIdx.x;
  if (idx >= FEAT_ * 256) return;
  int j = idx >> 8, c = idx & 255;
  float w = (c < NHID_) ? wl[j * NHID_ + c] : wr[j * NHID_ + (c - NHID_)];
  if (j < 12) w *= 1.0f / __int_as_float(scale_i[j]);
  W[idx] = w;
}

// WC = [wl | wr]  (128 x 256)
__global__ void combine_w_kernel(const float* __restrict__ wl, const float* __restrict__ wr,
                                 float* __restrict__ W) {
  int idx = blockIdx.x * blockDim.x + threadIdx.x;
  if (idx >= NHID_ * 256) return;
  int j = idx >> 8, c = idx & 255;
  W[idx] = (c < NHID_) ? wl[j * NHID_ + c] : wr[j * NHID_ + (c - NHID_)];
}

// C[M x 256] = A[M x K] @ B[K x 256]; f32, 64x64 tile, 4x4 per thread
__global__ __launch_bounds__(256) void gemm_kernel(const float* __restrict__ A,
                                                   const float* __restrict__ B,
                                                   float* __restrict__ C, int M, int K) {
  __shared__ float As[16][65];
  __shared__ float Bs[16][65];
  int bm = blockIdx.x * 64;
  int bn = blockIdx.y * 64;
  int tx = threadIdx.x & 15, ty = threadIdx.x >> 4;
  float acc[4][4] = {};
  for (int k0 = 0; k0 < K; k0 += 16) {
    for (int t = threadIdx.x; t < 64 * 16; t += 256) {
      int r = t >> 4, kk = t & 15;
      int gr = bm + r, gk = k0 + kk;
      As[kk][r] = (gr < M && gk < K) ? A[(size_t)gr * K + gk] : 0.f;
    }
    for (int t = threadIdx.x; t < 16 * 64; t += 256) {
      int kk = t >> 6, c = t & 63;
      int gk = k0 + kk;
      Bs[kk][c] = (gk < K) ? B[(size_t)gk * 256 + bn + c] : 0.f;
    }
    __syncthreads();
#pragma unroll
    for (int kk = 0; kk < 16; kk++) {
      float a[4], b[4];
#pragma unroll
      for (int i = 0; i < 4; i++) a[i] = As[kk][ty * 4 + i];
#pragma unroll
      for (int j = 0; j < 4; j++) b[j] = Bs[kk][tx * 4 + j];
#pragma unroll
      for (int i = 0; i < 4; i++)
#pragma unroll
        for (int j = 0; j < 4; j++) acc[i][j] += a[i] * b[j];
    }
    __syncthreads();
  }
  for (int i = 0; i < 4; i++) {
    int gr = bm + ty * 4 + i;
    if (gr >= M) continue;
    for (int j = 0; j < 4; j++)
      C[(size_t)gr * 256 + bn + tx * 4 + j] = acc[i][j];
  }
}

// agg[dst] += Y[src]*m (128 dims; Y row stride 256), cnt[dst] += m.  One wave per edge.
__global__ void edge_agg_kernel(const float* __restrict__ Y,
                                const int* __restrict__ src, const int* __restrict__ dst,
                                const float* __restrict__ m,
                                float* __restrict__ agg, float* __restrict__ cnt, int nEdge) {
  int wid = threadIdx.x >> 6, lane = threadIdx.x & 63;
  int e = blockIdx.x * 4 + wid;
  if (e >= nEdge) return;
  float me = m ? m[e] : 1.0f;
  if (me == 0.f) return;
  int s = src[e], d = dst[e];
  float v0 = Y[(size_t)s * 256 + lane] * me;
  float v1 = Y[(size_t)s * 256 + 64 + lane] * me;
  atomicAdd(agg + (size_t)d * 128 + lane, v0);
  atomicAdd(agg + (size_t)d * 128 + 64 + lane, v1);
  if (lane == 0) atomicAdd(cnt + d, me);
}

// x = relu(agg/max(cnt,1) + bl + Z)   (in-place into agg; Z = YZ[:,128:256])
__global__ void sage_finish_kernel(float* __restrict__ aggx, const float* __restrict__ cnt,
                                   const float* __restrict__ bl, const float* __restrict__ YZ,
                                   int M) {
  int idx = blockIdx.x * blockDim.x + threadIdx.x;
  if (idx >= M * NHID_) return;
  int i = idx >> 7, j = idx & 127;
  float v = aggx[idx] / fmaxf(cnt[i], 1.f) + bl[j] + YZ[(size_t)i * 256 + 128 + j];
  aggx[idx] = fmaxf(v, 0.f);
}

// T[i] = x[i]·wrel, R[i] = x[i]·wroot  (one wave per row)
__global__ void dots_kernel(const float* __restrict__ X, const float* __restrict__ wrel,
                            const float* __restrict__ wroot, float* __restrict__ T,
                            float* __restrict__ R, int M) {
  int wid = threadIdx.x >> 6, lane = threadIdx.x & 63;
  int i = blockIdx.x * 4 + wid;
  if (i >= M) return;
  float x0 = X[(size_t)i * 128 + lane], x1 = X[(size_t)i * 128 + 64 + lane];
  float t = x0 * wrel[lane] + x1 * wrel[64 + lane];
  float r = x0 * wroot[lane] + x1 * wroot[64 + lane];
  for (int off = 32; off > 0; off >>= 1) {
    t += __shfl_down(t, off);
    r += __shfl_down(r, off);
  }
  if (lane == 0) { T[i] = t; R[i] = r; }
}

__global__ void sagg_edge_kernel(const float* __restrict__ T, const int* __restrict__ src,
                                 const int* __restrict__ dst, const float* __restrict__ m,
                                 float* __restrict__ sagg, int nEdge) {
  int e = blockIdx.x * blockDim.x + threadIdx.x;
  if (e >= nEdge) return;
  float me = m ? m[e] : 1.0f;
  if (me == 0.f) return;
  atomicAdd(sagg + dst[e], T[src[e]] * me);
}

__global__ void score_finish_kernel(const float* __restrict__ sagg, const float* __restrict__ R,
                                    const float* __restrict__ brel, float* __restrict__ score,
                                    int M) {
  int i = blockIdx.x * blockDim.x + threadIdx.x;
  if (i < M) score[i] = sagg[i] + brel[0] + R[i];
}

// one block per graph: bitonic sort (desc) of n scores (padded to NP), emit top-k set
template <int NP>
__global__ void topk_kernel(const float* __restrict__ score, int n, int k,
                            float* __restrict__ sel, int* __restrict__ oldidx,
                            int* __restrict__ mapping) {
  __shared__ float val[NP];
  __shared__ int ind[NP];
  int g = blockIdx.x;
  for (int t = threadIdx.x; t < NP; t += blockDim.x) {
    val[t] = (t < n) ? score[g * n + t] : -FLT_MAX;
    ind[t] = t;
  }
  __syncthreads();
  for (int kk = 2; kk <= NP; kk <<= 1) {
    for (int j = kk >> 1; j > 0; j >>= 1) {
      for (int i = threadIdx.x; i < NP; i += blockDim.x) {
        int ixj = i ^ j;
        if (ixj > i) {
          bool desc = ((i & kk) == 0);
          float vi = val[i], vj = val[ixj];
          if (desc ? (vi < vj) : (vi > vj)) {
            val[i] = vj; val[ixj] = vi;
            int tmp = ind[i]; ind[i] = ind[ixj]; ind[ixj] = tmp;
          }
        }
      }
      __syncthreads();
    }
  }
  for (int t = threadIdx.x; t < k; t += blockDim.x) {
    int gid = g * k + t;
    sel[gid] = val[t];
    int node = ind[t];
    oldidx[gid] = g * n + node;
    mapping[g * n + node] = gid;
  }
}

__global__ void gather_gate_kernel(const float* __restrict__ X, const float* __restrict__ sel,
                                   const int* __restrict__ oldidx, float* __restrict__ NX) {
  int v = blockIdx.x, c = threadIdx.x;  // 128 threads
  float gate = tanhf(sel[v]);
  NX[(size_t)v * 128 + c] = X[(size_t)oldidx[v] * 128 + c] * gate;
}

__global__ void edge_remap_kernel(const int* __restrict__ src, const int* __restrict__ dst,
                                  const float* __restrict__ m, const int* __restrict__ mapping,
                                  int* __restrict__ nsrc, int* __restrict__ ndst,
                                  float* __restrict__ nm, int nEdge) {
  int e = blockIdx.x * blockDim.x + threadIdx.x;
  if (e >= nEdge) return;
  int ns = mapping[src[e]], nd = mapping[dst[e]];
  float me = m ? m[e] : 1.0f;
  nm[e] = (ns >= 0 && nd >= 0) ? me : 0.f;
  nsrc[e] = max(ns, 0);
  ndst[e] = max(nd, 0);
}

// H[g, 0:128] += max over k rows; H[g, 128:256] += mean over k rows
__global__ void readout_kernel(const float* __restrict__ NX, float* __restrict__ H, int k) {
  int g = blockIdx.x, c = threadIdx.x;  // 128 threads
  float mx = -FLT_MAX, sm = 0.f;
  for (int j = 0; j < k; j++) {
    float v = NX[((size_t)g * k + j) * 128 + c];
    mx = fmaxf(mx, v);
    sm += v;
  }
  H[g * 256 + c] += mx;
  H[g * 256 + 128 + c] += sm / (float)k;
}

__global__ void head_kernel(const float* __restrict__ H, const int* __restrict__ gpp,
                            const float* __restrict__ lin1_w, const float* __restrict__ lin1_b,
                            const float* __restrict__ lin2_w, const float* __restrict__ lin2_b,
                            const float* __restrict__ grade_w, const float* __restrict__ grade_b,
                            const float* __restrict__ haz_w, const float* __restrict__ haz_b,
                            float* __restrict__ out) {
  __shared__ float pooled[P_][256];
  __shared__ float h1[P_][NHID_];
  __shared__ float feats[P_][GDIM_];
  __shared__ int off[P_ + 1];
  int tid = threadIdx.x;
  if (tid == 0) {
    off[0] = 0;
    for (int p = 0; p < P_; p++) off[p + 1] = min(off[p] + gpp[p], G_);
  }
  __syncthreads();
  for (int idx = tid; idx < P_ * 256; idx += blockDim.x) {
    int p = idx >> 8, c = idx & 255;
    int a = off[p], b = (p == P_ - 1) ? G_ : off[p + 1];
    float s = 0.f;
    for (int gq = a; gq < b; gq++) s += H[gq * 256 + c];
    pooled[p][c] = s / (float)gpp[p];
  }
  __syncthreads();
  for (int idx = tid; idx < P_ * NHID_; idx += blockDim.x) {
    int p = idx >> 7, o = idx & 127;
    float acc = lin1_b[o];
    for (int c = 0; c < 256; c++) acc += pooled[p][c] * lin1_w[c * NHID_ + o];
    h1[p][o] = fmaxf(acc, 0.f);
  }
  __syncthreads();
  for (int idx = tid; idx < P_ * GDIM_; idx += blockDim.x) {
    int p = idx / GDIM_, o = idx % GDIM_;
    float acc = lin2_b[o];
    for (int c = 0; c < NHID_; c++) acc += h1[p][c] * lin2_w[c * GDIM_ + o];
    float f = fmaxf(acc, 0.f);
    feats[p][o] = f;
    out[p * GDIM_ + o] = f;
  }
  __syncthreads();
  if (tid < P_) {
    int p = tid;
    float l[3];
    float mx = -FLT_MAX;
    for (int j = 0; j < 3; j++) {
      float acc = grade_b[j];
      for (int c = 0; c < GDIM_; c++) acc += feats[p][c] * grade_w[c * 3 + j];
      l[j] = acc;
      mx = fmaxf(mx, acc);
    }
    float se = 0.f;
    for (int j = 0; j < 3; j++) se += expf(l[j] - mx);
    float lse = mx + logf(se);
    for (int j = 0; j < 3; j++) out[P_ * GDIM_ + p * 3 + j] = l[j] - lse;
    float z = haz_b[0];
    for (int c = 0; c < GDIM_; c++) z += feats[p][c] * haz_w[c];
    out[P_ * GDIM_ + P_ * 3 + p] = 6.f / (1.f + expf(-z)) - 3.f;
  }
}

// ---------------- launch ----------------
extern "C" void kernel_launch(void* const* d_in, const int* in_sizes, int n_in,
                              void* d_out, int out_size, void* d_ws, size_t ws_size,
                              hipStream_t stream) {
  (void)in_sizes; (void)n_in; (void)out_size; (void)ws_size;
  const float* x  = (const float*)d_in[0];
  const int* ei   = (const int*)d_in[1];
  const int* gpp  = (const int*)d_in[2];
  const float* c_wl[3]    = {(const float*)d_in[3],  (const float*)d_in[9],  (const float*)d_in[15]};
  const float* c_bl[3]    = {(const float*)d_in[4],  (const float*)d_in[10], (const float*)d_in[16]};
  const float* c_wr[3]    = {(const float*)d_in[5],  (const float*)d_in[11], (const float*)d_in[17]};
  const float* p_wrel[3]  = {(const float*)d_in[6],  (const float*)d_in[12], (const float*)d_in[18]};
  const float* p_brel[3]  = {(const float*)d_in[7],  (const float*)d_in[13], (const float*)d_in[19]};
  const float* p_wroot[3] = {(const float*)d_in[8],  (const float*)d_in[14], (const float*)d_in[20]};
  const float* lin1_w = (const float*)d_in[21];
  const float* lin1_b = (const float*)d_in[22];
  const float* lin2_w = (const float*)d_in[23];
  const float* lin2_b = (const float*)d_in[24];
  const float* grade_w = (const float*)d_in[25];
  const float* grade_b = (const float*)d_in[26];
  const float* haz_w = (const float*)d_in[27];
  const float* haz_b = (const float*)d_in[28];

  float* ws = (float*)d_ws;
  float* SCALE = ws;                                   // 64 (int bits)
  float* W01   = SCALE + 64;                           // 1036*256
  float* WC    = W01 + (size_t)FEAT_ * 256;            // 128*256
  float* YZ    = WC + (size_t)NHID_ * 256;             // 50000*256
  float* AGG   = YZ + (size_t)M0_ * 256;               // 50000*128 (also holds x_l in place)
  float* NX    = AGG + (size_t)M0_ * 128;              // 10000*128
  float* CNT   = NX + (size_t)M1_ * 128;               // 50000
  float* T     = CNT + M0_;                            // 50000
  float* R     = T + M0_;                              // 50000
  float* SAGG  = R + M0_;                              // 50000
  float* SCORE = SAGG + M0_;                           // 50000
  float* SEL   = SCORE + M0_;                          // 10000
  int*   OLD   = (int*)(SEL + M1_);                    // 10000
  int*   MAP   = OLD + M1_;                            // 50000
  int*   E1S   = MAP + M0_;                            // 200000
  int*   E1D   = E1S + NEDGE;                          // 200000
  float* E1M   = (float*)(E1D + NEDGE);                // 200000
  int*   E2S   = (int*)(E1M + NEDGE);                  // 200000
  int*   E2D   = E2S + NEDGE;                          // 200000
  float* E2M   = (float*)(E2D + NEDGE);                // 200000
  float* H     = E2M + NEDGE;                          // 50*256

  const int* src0 = ei;
  const int* dst0 = ei + NEDGE;

  hipMemsetAsync(H, 0, G_ * 256 * sizeof(float), stream);
  hipMemsetAsync(SCALE, 0, 12 * sizeof(int), stream);

  // ---- layer 0 ----
  colmax_kernel<<<dim3(12, 32), 256, 0, stream>>>(x, (int*)SCALE);
  scale_w01_kernel<<<(FEAT_ * 256 + 255) / 256, 256, 0, stream>>>(c_wl[0], c_wr[0], (int*)SCALE, W01);
  gemm_kernel<<<dim3((M0_ + 63) / 64, 4), 256, 0, stream>>>(x, W01, YZ, M0_, FEAT_);
  hipMemsetAsync(AGG, 0, (size_t)M0_ * 128 * sizeof(float), stream);
  hipMemsetAsync(CNT, 0, M0_ * sizeof(float), stream);
  edge_agg_kernel<<<(NEDGE + 3) / 4, 256, 0, stream>>>(YZ, src0, dst0, nullptr, AGG, CNT, NEDGE);
  sage_finish_kernel<<<(M0_ * NHID_ + 255) / 256, 256, 0, stream>>>(AGG, CNT, c_bl[0], YZ, M0_);
  dots_kernel<<<(M0_ + 3) / 4, 256, 0, stream>>>(AGG, p_wrel[0], p_wroot[0], T, R, M0_);
  hipMemsetAsync(SAGG, 0, M0_ * sizeof(float), stream);
  sagg_edge_kernel<<<(NEDGE + 255) / 256, 256, 0, stream>>>(T, src0, dst0, nullptr, SAGG, NEDGE);
  score_finish_kernel<<<(M0_ + 255) / 256, 256, 0, stream>>>(SAGG, R, p_brel[0], SCORE, M0_);
  hipMemsetAsync(MAP, 0xFF, M0_ * sizeof(int), stream);
  topk_kernel<1024><<<G_, 256, 0, stream>>>(SCORE, N0_, K0_, SEL, OLD, MAP);
  gather_gate_kernel<<<M1_, 128, 0, stream>>>(AGG, SEL, OLD, NX);
  edge_remap_kernel<<<(NEDGE + 255) / 256, 256, 0, stream>>>(src0, dst0, nullptr, MAP, E1S, E1D, E1M, NEDGE);
  readout_kernel<<<G_, 128, 0, stream>>>(NX, H, K0_);

  // ---- layer 1 ----
  combine_w_kernel<<<(NHID_ * 256 + 255) / 256, 256, 0, stream>>>(c_wl[1], c_wr[1], WC);
  gemm_kernel<<<dim3((M1_ + 63) / 64, 4), 256, 0, stream>>>(NX, WC, YZ, M1_, NHID_);
  hipMemsetAsync(AGG, 0, (size_t)M1_ * 128 * sizeof(float), stream);
  hipMemsetAsync(CNT, 0, M1_ * sizeof(float), stream);
  edge_agg_kernel<<<(NEDGE + 3) / 4, 256, 0, stream>>>(YZ, E1S, E1D, E1M, AGG, CNT, NEDGE);
  sage_finish_kernel<<<(M1_ * NHID_ + 255) / 256, 256, 0, stream>>>(AGG, CNT, c_bl[1], YZ, M1_);
  dots_kernel<<<(M1_ + 3) / 4, 256, 0, stream>>>(AGG, p_wrel[1], p_wroot[1], T, R, M1_);
  hipMemsetAsync(SAGG, 0, M1_ * sizeof(float), stream);
  sagg_edge_kernel<<<(NEDGE + 255) / 256, 256, 0, stream>>>(T, E1S, E1D, E1M, SAGG, NEDGE);
  score_finish_kernel<<<(M1_ + 255) / 256, 256, 0, stream>>>(SAGG, R, p_brel[1], SCORE, M1_);
  hipMemsetAsync(MAP, 0xFF, M1_ * sizeof(int), stream);
  topk_kernel<256><<<G_, 256, 0, stream>>>(SCORE, K0_, K1_, SEL, OLD, MAP);
  gather_gate_kernel<<<M2_, 128, 0, stream>>>(AGG, SEL, OLD, NX);
  edge_remap_kernel<<<(NEDGE + 255) / 256, 256, 0, stream>>>(E1S, E1D, E1M, MAP, E2S, E2D, E2M, NEDGE);
  readout_kernel<<<G_, 128, 0, stream>>>(NX, H, K1_);

  // ---- layer 2 ----
  combine_w_kernel<<<(NHID_ * 256 + 255) / 256, 256, 0, stream>>>(c_wl[2], c_wr[2], WC);
  gemm_kernel<<<dim3((M2_ + 63) / 64, 4), 256, 0, stream>>>(NX, WC, YZ, M2_, NHID_);
  hipMemsetAsync(AGG, 0, (size_t)M2_ * 128 * sizeof(float), stream);
  hipMemsetAsync(CNT, 0, M2_ * sizeof(float), stream);
  edge_agg_kernel<<<(NEDGE + 3) / 4, 256, 0, stream>>>(YZ, E2S, E2D, E2M, AGG, CNT, NEDGE);
  sage_finish_kernel<<<(M2_ * NHID_ + 255) / 256, 256, 0, stream>>>(AGG, CNT, c_bl[2], YZ, M2_);
  dots_kernel<<<(M2_ + 3) / 4, 256, 0, stream>>>(AGG, p_wrel[2], p_wroot[2], T, R, M2_);
  hipMemsetAsync(SAGG, 0, M2_ * sizeof(float), stream);
  sagg_edge_kernel<<<(NEDGE + 255) / 256, 256, 0, stream>>>(T, E2S, E2D, E2M, SAGG, NEDGE);
  score_finish_kernel<<<(M2_ + 255) / 256, 256, 0, stream>>>(SAGG, R, p_brel[2], SCORE, M2_);
  hipMemsetAsync(MAP, 0xFF, M2_ * sizeof(int), stream);
  topk_kernel<64><<<G_, 256, 0, stream>>>(SCORE, K1_, K2_, SEL, OLD, MAP);
  gather_gate_kernel<<<M3_, 128, 0, stream>>>(AGG, SEL, OLD, NX);
  readout_kernel<<<G_, 128, 0, stream>>>(NX, H, K2_);

  // ---- head ----
  head_kernel<<<1, 256, 0, stream>>>(H, gpp, lin1_w, lin1_b, lin2_w, lin2_b,
                                     grade_w, grade_b, haz_w, haz_b, (float*)d_out);
}

// Round 4
// 555.710 us; speedup vs baseline: 2.1622x; 2.1622x over previous
//
#include <hip/hip_runtime.h>
#include <math.h>
#include <cfloat>

// ---------------- problem constants ----------------
#define G_    50
#define N0_   1000
#define NEDGE 200000
#define P_    10
#define FEAT_ 1036
#define NHID_ 128
#define GDIM_ 32
#define K0_   200          // ceil(0.2*1000)
#define K1_   40           // ceil(0.2*200)
#define K2_   8            // ceil(0.2*40)
#define M0_   (G_*N0_)     // 50000
#define M1_   (G_*K0_)     // 10000
#define M2_   (G_*K1_)     // 2000
#define M3_   (G_*K2_)     // 400

#define KPAD_ 1056         // 1036 padded to multiple of 32
#define MPAD_ 50048        // 50000 padded to multiple of 128

typedef __attribute__((ext_vector_type(8))) short s16x8;
typedef __attribute__((ext_vector_type(4))) float f32x4;

__device__ __forceinline__ unsigned f2bf1(float f) {   // bf16 bits in low 16, RNE
  unsigned u = __float_as_uint(f);
  return (u + 0x7FFFu + ((u >> 16) & 1u)) >> 16;
}
__device__ __forceinline__ unsigned packbf(float a, float b) {
  return f2bf1(a) | (f2bf1(b) << 16);
}

__device__ __forceinline__ void gload_lds16(const void* g, void* l) {
  __builtin_amdgcn_global_load_lds((const __attribute__((address_space(1))) void*)g,
                                   (__attribute__((address_space(3))) void*)l, 16, 0, 0);
}

// ---------------- kernels ----------------

// max over rows of x[:, c] for c<12, via atomicMax on int bits (values >= 0)
__global__ void colmax_kernel(const float* __restrict__ x, int* __restrict__ scale_i) {
  int c = blockIdx.x;                 // 0..11
  int chunk = blockIdx.y;             // 0..31
  const int rows_per = (M0_ + gridDim.y - 1) / gridDim.y;
  int r0 = chunk * rows_per;
  int r1 = min(r0 + rows_per, M0_);
  float mx = 0.f;
  for (int r = r0 + (int)threadIdx.x; r < r1; r += blockDim.x)
    mx = fmaxf(mx, x[(size_t)r * FEAT_ + c]);
  __shared__ float red[256];
  red[threadIdx.x] = mx;
  __syncthreads();
  for (int s = 128; s > 0; s >>= 1) {
    if ((int)threadIdx.x < s) red[threadIdx.x] = fmaxf(red[threadIdx.x], red[threadIdx.x + s]);
    __syncthreads();
  }
  if (threadIdx.x == 0) atomicMax(scale_i + c, __float_as_int(red[0]));
}

// WT[c][j] = bf16( scaled W01[j][c] ), c in [0,256), j in [0,1056) (pad j>=1036 -> 0)
__global__ void build_wt_kernel(const float* __restrict__ wl, const float* __restrict__ wr,
                                const int* __restrict__ scale_i, unsigned short* __restrict__ WT) {
  int idx = blockIdx.x * blockDim.x + threadIdx.x;
  if (idx >= 256 * KPAD_) return;
  int c = idx / KPAD_, j = idx % KPAD_;
  float w = 0.f;
  if (j < FEAT_) {
    w = (c < NHID_) ? wl[j * NHID_ + c] : wr[j * NHID_ + (c - NHID_)];
    if (j < 12) w *= 1.0f / __int_as_float(scale_i[j]);
  }
  WT[idx] = (unsigned short)f2bf1(w);
}

// C[M x 256] = A(f32)[M x FEAT] @ WT^T  (WT [256][KPAD] bf16 row-major).
// 128x256 tile (grid.x covers M; N=256 in one block). 4 waves 2x2; each wave 64x128.
// A staged f32->bf16 via registers+ds_write; B staged via global_load_lds.
__global__ __launch_bounds__(256) void mfma_gemm_kernel(const float* __restrict__ A,
                                                        const unsigned short* __restrict__ WT,
                                                        float* __restrict__ C, int M) {
  __shared__ unsigned short As[128 * 32];   // [row][k]
  __shared__ unsigned short Bs[256 * 32];   // [col][k]
  const int bm = blockIdx.x * 128;
  const int tid = threadIdx.x, wave = tid >> 6, lane = tid & 63;
  const int wr = wave >> 1, wc = wave & 1;
  const int lhi = lane >> 4, llo = lane & 15;
  const int arow = tid >> 1, ahalf = tid & 1;   // A staging: 16 k-elems per thread
  f32x4 acc[4][8] = {};

  for (int k0 = 0; k0 < KPAD_; k0 += 32) {
    // ---- stage B: 256x32 bf16 = 1024 16B chunks, 4 per thread via global_load_lds
#pragma unroll
    for (int it = 0; it < 4; it++) {
      int c = it * 256 + wave * 64 + lane;
      int row = c >> 2, cb = c & 3;
      gload_lds16(WT + (size_t)row * KPAD_ + k0 + cb * 8, Bs + (size_t)(it * 256 + wave * 64) * 8);
    }
    // ---- stage A: 128 rows x 32 k f32 -> bf16
    {
      int gr = bm + arow;
      int kb = k0 + ahalf * 16;
      float f[16];
      if (gr < M && kb + 16 <= FEAT_) {
        const float4* ap = (const float4*)(A + (size_t)gr * FEAT_ + kb);
        float4 v0 = ap[0], v1 = ap[1], v2 = ap[2], v3 = ap[3];
        f[0]=v0.x; f[1]=v0.y; f[2]=v0.z; f[3]=v0.w;
        f[4]=v1.x; f[5]=v1.y; f[6]=v1.z; f[7]=v1.w;
        f[8]=v2.x; f[9]=v2.y; f[10]=v2.z; f[11]=v2.w;
        f[12]=v3.x; f[13]=v3.y; f[14]=v3.z; f[15]=v3.w;
      } else {
        const float* ap = A + (size_t)gr * FEAT_ + kb;
#pragma unroll
        for (int j = 0; j < 16; j++)
          f[j] = (gr < M && kb + j < FEAT_) ? ap[j] : 0.f;
      }
      uint4 p0, p1;
      p0.x = packbf(f[0], f[1]);  p0.y = packbf(f[2], f[3]);
      p0.z = packbf(f[4], f[5]);  p0.w = packbf(f[6], f[7]);
      p1.x = packbf(f[8], f[9]);  p1.y = packbf(f[10], f[11]);
      p1.z = packbf(f[12], f[13]); p1.w = packbf(f[14], f[15]);
      *(uint4*)&As[arow * 32 + ahalf * 16] = p0;
      *(uint4*)&As[arow * 32 + ahalf * 16 + 8] = p1;
    }
    __syncthreads();   // drains vmcnt (gload_lds) + lgkmcnt (ds_write)

    s16x8 a[4], b[8];
#pragma unroll
    for (int mt = 0; mt < 4; mt++)
      a[mt] = *(const s16x8*)&As[(wr * 64 + mt * 16 + llo) * 32 + lhi * 8];
#pragma unroll
    for (int nt = 0; nt < 8; nt++)
      b[nt] = *(const s16x8*)&Bs[(wc * 128 + nt * 16 + llo) * 32 + lhi * 8];
#pragma unroll
    for (int mt = 0; mt < 4; mt++)
#pragma unroll
      for (int nt = 0; nt < 8; nt++)
        acc[mt][nt] = __builtin_amdgcn_mfma_f32_16x16x32_bf16(a[mt], b[nt], acc[mt][nt], 0, 0, 0);
    __syncthreads();
  }

  // C/D layout: col = lane&15, row = (lane>>4)*4 + q   [m89-verified]
#pragma unroll
  for (int mt = 0; mt < 4; mt++) {
#pragma unroll
    for (int q = 0; q < 4; q++) {
      int row = bm + wr * 64 + mt * 16 + lhi * 4 + q;
      if (row < M) {
#pragma unroll
        for (int nt = 0; nt < 8; nt++)
          C[(size_t)row * 256 + wc * 128 + nt * 16 + llo] = acc[mt][nt][q];
      }
    }
  }
}

// WC = [wl | wr]  (128 x 256)
__global__ void combine_w_kernel(const float* __restrict__ wl, const float* __restrict__ wr,
                                 float* __restrict__ W) {
  int idx = blockIdx.x * blockDim.x + threadIdx.x;
  if (idx >= NHID_ * 256) return;
  int j = idx >> 8, c = idx & 255;
  W[idx] = (c < NHID_) ? wl[j * NHID_ + c] : wr[j * NHID_ + (c - NHID_)];
}

// C[M x 256] = A[M x K] @ B[K x 256]; f32, 64x64 tile, 4x4 per thread (layers 1,2)
__global__ __launch_bounds__(256) void gemm_kernel(const float* __restrict__ A,
                                                   const float* __restrict__ B,
                                                   float* __restrict__ C, int M, int K) {
  __shared__ float As[16][65];
  __shared__ float Bs[16][65];
  int bm = blockIdx.x * 64;
  int bn = blockIdx.y * 64;
  int tx = threadIdx.x & 15, ty = threadIdx.x >> 4;
  float acc[4][4] = {};
  for (int k0 = 0; k0 < K; k0 += 16) {
    for (int t = threadIdx.x; t < 64 * 16; t += 256) {
      int r = t >> 4, kk = t & 15;
      int gr = bm + r, gk = k0 + kk;
      As[kk][r] = (gr < M && gk < K) ? A[(size_t)gr * K + gk] : 0.f;
    }
    for (int t = threadIdx.x; t < 16 * 64; t += 256) {
      int kk = t >> 6, c = t & 63;
      int gk = k0 + kk;
      Bs[kk][c] = (gk < K) ? B[(size_t)gk * 256 + bn + c] : 0.f;
    }
    __syncthreads();
#pragma unroll
    for (int kk = 0; kk < 16; kk++) {
      float a[4], b[4];
#pragma unroll
      for (int i = 0; i < 4; i++) a[i] = As[kk][ty * 4 + i];
#pragma unroll
      for (int j = 0; j < 4; j++) b[j] = Bs[kk][tx * 4 + j];
#pragma unroll
      for (int i = 0; i < 4; i++)
#pragma unroll
        for (int j = 0; j < 4; j++) acc[i][j] += a[i] * b[j];
    }
    __syncthreads();
  }
  for (int i = 0; i < 4; i++) {
    int gr = bm + ty * 4 + i;
    if (gr >= M) continue;
    for (int j = 0; j < 4; j++)
      C[(size_t)gr * 256 + bn + tx * 4 + j] = acc[i][j];
  }
}

// agg[dst] += Y[src]*m (128 dims; Y row stride 256), cnt[dst] += m.  One wave per edge.
__global__ void edge_agg_kernel(const float* __restrict__ Y,
                                const int* __restrict__ src, const int* __restrict__ dst,
                                const float* __restrict__ m,
                                float* __restrict__ agg, float* __restrict__ cnt, int nEdge) {
  int wid = threadIdx.x >> 6, lane = threadIdx.x & 63;
  int e = blockIdx.x * 4 + wid;
  if (e >= nEdge) return;
  float me = m ? m[e] : 1.0f;
  if (me == 0.f) return;
  int s = src[e], d = dst[e];
  float v0 = Y[(size_t)s * 256 + lane] * me;
  float v1 = Y[(size_t)s * 256 + 64 + lane] * me;
  atomicAdd(agg + (size_t)d * 128 + lane, v0);
  atomicAdd(agg + (size_t)d * 128 + 64 + lane, v1);
  if (lane == 0) atomicAdd(cnt + d, me);
}

// x = relu(agg/max(cnt,1) + bl + Z)   (in-place into agg; Z = YZ[:,128:256])
__global__ void sage_finish_kernel(float* __restrict__ aggx, const float* __restrict__ cnt,
                                   const float* __restrict__ bl, const float* __restrict__ YZ,
                                   int M) {
  int idx = blockIdx.x * blockDim.x + threadIdx.x;
  if (idx >= M * NHID_) return;
  int i = idx >> 7, j = idx & 127;
  float v = aggx[idx] / fmaxf(cnt[i], 1.f) + bl[j] + YZ[(size_t)i * 256 + 128 + j];
  aggx[idx] = fmaxf(v, 0.f);
}

// T[i] = x[i]·wrel, R[i] = x[i]·wroot  (one wave per row)
__global__ void dots_kernel(const float* __restrict__ X, const float* __restrict__ wrel,
                            const float* __restrict__ wroot, float* __restrict__ T,
                            float* __restrict__ R, int M) {
  int wid = threadIdx.x >> 6, lane = threadIdx.x & 63;
  int i = blockIdx.x * 4 + wid;
  if (i >= M) return;
  float x0 = X[(size_t)i * 128 + lane], x1 = X[(size_t)i * 128 + 64 + lane];
  float t = x0 * wrel[lane] + x1 * wrel[64 + lane];
  float r = x0 * wroot[lane] + x1 * wroot[64 + lane];
  for (int off = 32; off > 0; off >>= 1) {
    t += __shfl_down(t, off);
    r += __shfl_down(r, off);
  }
  if (lane == 0) { T[i] = t; R[i] = r; }
}

__global__ void sagg_edge_kernel(const float* __restrict__ T, const int* __restrict__ src,
                                 const int* __restrict__ dst, const float* __restrict__ m,
                                 float* __restrict__ sagg, int nEdge) {
  int e = blockIdx.x * blockDim.x + threadIdx.x;
  if (e >= nEdge) return;
  float me = m ? m[e] : 1.0f;
  if (me == 0.f) return;
  atomicAdd(sagg + dst[e], T[src[e]] * me);
}

__global__ void score_finish_kernel(const float* __restrict__ sagg, const float* __restrict__ R,
                                    const float* __restrict__ brel, float* __restrict__ score,
                                    int M) {
  int i = blockIdx.x * blockDim.x + threadIdx.x;
  if (i < M) score[i] = sagg[i] + brel[0] + R[i];
}

// one block per graph: bitonic sort (desc) of n scores (padded to NP), emit top-k set
template <int NP>
__global__ void topk_kernel(const float* __restrict__ score, int n, int k,
                            float* __restrict__ sel, int* __restrict__ oldidx,
                            int* __restrict__ mapping) {
  __shared__ float val[NP];
  __shared__ int ind[NP];
  int g = blockIdx.x;
  for (int t = threadIdx.x; t < NP; t += blockDim.x) {
    val[t] = (t < n) ? score[g * n + t] : -FLT_MAX;
    ind[t] = t;
  }
  __syncthreads();
  for (int kk = 2; kk <= NP; kk <<= 1) {
    for (int j = kk >> 1; j > 0; j >>= 1) {
      for (int i = threadIdx.x; i < NP; i += blockDim.x) {
        int ixj = i ^ j;
        if (ixj > i) {
          bool desc = ((i & kk) == 0);
          float vi = val[i], vj = val[ixj];
          if (desc ? (vi < vj) : (vi > vj)) {
            val[i] = vj; val[ixj] = vi;
            int tmp = ind[i]; ind[i] = ind[ixj]; ind[ixj] = tmp;
          }
        }
      }
      __syncthreads();
    }
  }
  for (int t = threadIdx.x; t < k; t += blockDim.x) {
    int gid = g * k + t;
    sel[gid] = val[t];
    int node = ind[t];
    oldidx[gid] = g * n + node;
    mapping[g * n + node] = gid;
  }
}

__global__ void gather_gate_kernel(const float* __restrict__ X, const float* __restrict__ sel,
                                   const int* __restrict__ oldidx, float* __restrict__ NX) {
  int v = blockIdx.x, c = threadIdx.x;  // 128 threads
  float gate = tanhf(sel[v]);
  NX[(size_t)v * 128 + c] = X[(size_t)oldidx[v] * 128 + c] * gate;
}

__global__ void edge_remap_kernel(const int* __restrict__ src, const int* __restrict__ dst,
                                  const float* __restrict__ m, const int* __restrict__ mapping,
                                  int* __restrict__ nsrc, int* __restrict__ ndst,
                                  float* __restrict__ nm, int nEdge) {
  int e = blockIdx.x * blockDim.x + threadIdx.x;
  if (e >= nEdge) return;
  int ns = mapping[src[e]], nd = mapping[dst[e]];
  float me = m ? m[e] : 1.0f;
  nm[e] = (ns >= 0 && nd >= 0) ? me : 0.f;
  nsrc[e] = max(ns, 0);
  ndst[e] = max(nd, 0);
}

// H[g, 0:128] += max over k rows; H[g, 128:256] += mean over k rows
__global__ void readout_kernel(const float* __restrict__ NX, float* __restrict__ H, int k) {
  int g = blockIdx.x, c = threadIdx.x;  // 128 threads
  float mx = -FLT_MAX, sm = 0.f;
  for (int j = 0; j < k; j++) {
    float v = NX[((size_t)g * k + j) * 128 + c];
    mx = fmaxf(mx, v);
    sm += v;
  }
  H[g * 256 + c] += mx;
  H[g * 256 + 128 + c] += sm / (float)k;
}

__global__ void head_kernel(const float* __restrict__ H, const int* __restrict__ gpp,
                            const float* __restrict__ lin1_w, const float* __restrict__ lin1_b,
                            const float* __restrict__ lin2_w, const float* __restrict__ lin2_b,
                            const float* __restrict__ grade_w, const float* __restrict__ grade_b,
                            const float* __restrict__ haz_w, const float* __restrict__ haz_b,
                            float* __restrict__ out) {
  __shared__ float pooled[P_][256];
  __shared__ float h1[P_][NHID_];
  __shared__ float feats[P_][GDIM_];
  __shared__ int off[P_ + 1];
  int tid = threadIdx.x;
  if (tid == 0) {
    off[0] = 0;
    for (int p = 0; p < P_; p++) off[p + 1] = min(off[p] + gpp[p], G_);
  }
  __syncthreads();
  for (int idx = tid; idx < P_ * 256; idx += blockDim.x) {
    int p = idx >> 8, c = idx & 255;
    int a = off[p], b = (p == P_ - 1) ? G_ : off[p + 1];
    float s = 0.f;
    for (int gq = a; gq < b; gq++) s += H[gq * 256 + c];
    pooled[p][c] = s / (float)gpp[p];
  }
  __syncthreads();
  for (int idx = tid; idx < P_ * NHID_; idx += blockDim.x) {
    int p = idx >> 7, o = idx & 127;
    float acc = lin1_b[o];
    for (int c = 0; c < 256; c++) acc += pooled[p][c] * lin1_w[c * NHID_ + o];
    h1[p][o] = fmaxf(acc, 0.f);
  }
  __syncthreads();
  for (int idx = tid; idx < P_ * GDIM_; idx += blockDim.x) {
    int p = idx / GDIM_, o = idx % GDIM_;
    float acc = lin2_b[o];
    for (int c = 0; c < NHID_; c++) acc += h1[p][c] * lin2_w[c * GDIM_ + o];
    float f = fmaxf(acc, 0.f);
    feats[p][o] = f;
    out[p * GDIM_ + o] = f;
  }
  __syncthreads();
  if (tid < P_) {
    int p = tid;
    float l[3];
    float mx = -FLT_MAX;
    for (int j = 0; j < 3; j++) {
      float acc = grade_b[j];
      for (int c = 0; c < GDIM_; c++) acc += feats[p][c] * grade_w[c * 3 + j];
      l[j] = acc;
      mx = fmaxf(mx, acc);
    }
    float se = 0.f;
    for (int j = 0; j < 3; j++) se += expf(l[j] - mx);
    float lse = mx + logf(se);
    for (int j = 0; j < 3; j++) out[P_ * GDIM_ + p * 3 + j] = l[j] - lse;
    float z = haz_b[0];
    for (int c = 0; c < GDIM_; c++) z += feats[p][c] * haz_w[c];
    out[P_ * GDIM_ + P_ * 3 + p] = 6.f / (1.f + expf(-z)) - 3.f;
  }
}

// ---------------- launch ----------------
extern "C" void kernel_launch(void* const* d_in, const int* in_sizes, int n_in,
                              void* d_out, int out_size, void* d_ws, size_t ws_size,
                              hipStream_t stream) {
  (void)in_sizes; (void)n_in; (void)out_size; (void)ws_size;
  const float* x  = (const float*)d_in[0];
  const int* ei   = (const int*)d_in[1];
  const int* gpp  = (const int*)d_in[2];
  const float* c_wl[3]    = {(const float*)d_in[3],  (const float*)d_in[9],  (const float*)d_in[15]};
  const float* c_bl[3]    = {(const float*)d_in[4],  (const float*)d_in[10], (const float*)d_in[16]};
  const float* c_wr[3]    = {(const float*)d_in[5],  (const float*)d_in[11], (const float*)d_in[17]};
  const float* p_wrel[3]  = {(const float*)d_in[6],  (const float*)d_in[12], (const float*)d_in[18]};
  const float* p_brel[3]  = {(const float*)d_in[7],  (const float*)d_in[13], (const float*)d_in[19]};
  const float* p_wroot[3] = {(const float*)d_in[8],  (const float*)d_in[14], (const float*)d_in[20]};
  const float* lin1_w = (const float*)d_in[21];
  const float* lin1_b = (const float*)d_in[22];
  const float* lin2_w = (const float*)d_in[23];
  const float* lin2_b = (const float*)d_in[24];
  const float* grade_w = (const float*)d_in[25];
  const float* grade_b = (const float*)d_in[26];
  const float* haz_w = (const float*)d_in[27];
  const float* haz_b = (const float*)d_in[28];

  // ---- workspace layout (256B-aligned blocks), ~85 MB total ----
  char* wsb = (char*)d_ws;
  size_t off = 0;
  auto alloc = [&](size_t bytes) -> void* {
    void* p = wsb + off;
    off += (bytes + 255) & ~(size_t)255;
    return p;
  };
  int*            SCALE = (int*)alloc(64 * 4);
  float*          WC    = (float*)alloc((size_t)NHID_ * 256 * 4);
  unsigned short* WT    = (unsigned short*)alloc((size_t)256 * KPAD_ * 2);
  float*          YZ    = (float*)alloc((size_t)M0_ * 256 * 4);
  float*          H     = (float*)alloc((size_t)G_ * 256 * 4);
  float* AGG   = (float*)alloc((size_t)M0_ * 128 * 4);
  float* NX    = (float*)alloc((size_t)M1_ * 128 * 4);
  float* CNT   = (float*)alloc((size_t)M0_ * 4);
  float* T     = (float*)alloc((size_t)M0_ * 4);
  float* R     = (float*)alloc((size_t)M0_ * 4);
  float* SAGG  = (float*)alloc((size_t)M0_ * 4);
  float* SCORE = (float*)alloc((size_t)M0_ * 4);
  float* SEL   = (float*)alloc((size_t)M1_ * 4);
  int*   OLD   = (int*)alloc((size_t)M1_ * 4);
  int*   MAP   = (int*)alloc((size_t)M0_ * 4);
  int*   E1S   = (int*)alloc((size_t)NEDGE * 4);
  int*   E1D   = (int*)alloc((size_t)NEDGE * 4);
  float* E1M   = (float*)alloc((size_t)NEDGE * 4);
  int*   E2S   = (int*)alloc((size_t)NEDGE * 4);
  int*   E2D   = (int*)alloc((size_t)NEDGE * 4);
  float* E2M   = (float*)alloc((size_t)NEDGE * 4);

  const int* src0 = ei;
  const int* dst0 = ei + NEDGE;

  hipMemsetAsync(H, 0, G_ * 256 * sizeof(float), stream);
  hipMemsetAsync(SCALE, 0, 12 * sizeof(int), stream);

  // ---- layer 0: bf16 MFMA GEMM (A converted on the fly) ----
  colmax_kernel<<<dim3(12, 32), 256, 0, stream>>>(x, SCALE);
  build_wt_kernel<<<(256 * KPAD_ + 255) / 256, 256, 0, stream>>>(c_wl[0], c_wr[0], SCALE, WT);
  mfma_gemm_kernel<<<MPAD_ / 128, 256, 0, stream>>>(x, WT, YZ, M0_);
  hipMemsetAsync(AGG, 0, (size_t)M0_ * 128 * sizeof(float), stream);
  hipMemsetAsync(CNT, 0, M0_ * sizeof(float), stream);
  edge_agg_kernel<<<(NEDGE + 3) / 4, 256, 0, stream>>>(YZ, src0, dst0, nullptr, AGG, CNT, NEDGE);
  sage_finish_kernel<<<(M0_ * NHID_ + 255) / 256, 256, 0, stream>>>(AGG, CNT, c_bl[0], YZ, M0_);
  dots_kernel<<<(M0_ + 3) / 4, 256, 0, stream>>>(AGG, p_wrel[0], p_wroot[0], T, R, M0_);
  hipMemsetAsync(SAGG, 0, M0_ * sizeof(float), stream);
  sagg_edge_kernel<<<(NEDGE + 255) / 256, 256, 0, stream>>>(T, src0, dst0, nullptr, SAGG, NEDGE);
  score_finish_kernel<<<(M0_ + 255) / 256, 256, 0, stream>>>(SAGG, R, p_brel[0], SCORE, M0_);
  hipMemsetAsync(MAP, 0xFF, M0_ * sizeof(int), stream);
  topk_kernel<1024><<<G_, 256, 0, stream>>>(SCORE, N0_, K0_, SEL, OLD, MAP);
  gather_gate_kernel<<<M1_, 128, 0, stream>>>(AGG, SEL, OLD, NX);
  edge_remap_kernel<<<(NEDGE + 255) / 256, 256, 0, stream>>>(src0, dst0, nullptr, MAP, E1S, E1D, E1M, NEDGE);
  readout_kernel<<<G_, 128, 0, stream>>>(NX, H, K0_);

  // ---- layer 1 ----
  combine_w_kernel<<<(NHID_ * 256 + 255) / 256, 256, 0, stream>>>(c_wl[1], c_wr[1], WC);
  gemm_kernel<<<dim3((M1_ + 63) / 64, 4), 256, 0, stream>>>(NX, WC, YZ, M1_, NHID_);
  hipMemsetAsync(AGG, 0, (size_t)M1_ * 128 * sizeof(float), stream);
  hipMemsetAsync(CNT, 0, M1_ * sizeof(float), stream);
  edge_agg_kernel<<<(NEDGE + 3) / 4, 256, 0, stream>>>(YZ, E1S, E1D, E1M, AGG, CNT, NEDGE);
  sage_finish_kernel<<<(M1_ * NHID_ + 255) / 256, 256, 0, stream>>>(AGG, CNT, c_bl[1], YZ, M1_);
  dots_kernel<<<(M1_ + 3) / 4, 256, 0, stream>>>(AGG, p_wrel[1], p_wroot[1], T, R, M1_);
  hipMemsetAsync(SAGG, 0, M1_ * sizeof(float), stream);
  sagg_edge_kernel<<<(NEDGE + 255) / 256, 256, 0, stream>>>(T, E1S, E1D, E1M, SAGG, NEDGE);
  score_finish_kernel<<<(M1_ + 255) / 256, 256, 0, stream>>>(SAGG, R, p_brel[1], SCORE, M1_);
  hipMemsetAsync(MAP, 0xFF, M1_ * sizeof(int), stream);
  topk_kernel<256><<<G_, 256, 0, stream>>>(SCORE, K0_, K1_, SEL, OLD, MAP);
  gather_gate_kernel<<<M2_, 128, 0, stream>>>(AGG, SEL, OLD, NX);
  edge_remap_kernel<<<(NEDGE + 255) / 256, 256, 0, stream>>>(E1S, E1D, E1M, MAP, E2S, E2D, E2M, NEDGE);
  readout_kernel<<<G_, 128, 0, stream>>>(NX, H, K1_);

  // ---- layer 2 ----
  combine_w_kernel<<<(NHID_ * 256 + 255) / 256, 256, 0, stream>>>(c_wl[2], c_wr[2], WC);
  gemm_kernel<<<dim3((M2_ + 63) / 64, 4), 256, 0, stream>>>(NX, WC, YZ, M2_, NHID_);
  hipMemsetAsync(AGG, 0, (size_t)M2_ * 128 * sizeof(float), stream);
  hipMemsetAsync(CNT, 0, M2_ * sizeof(float), stream);
  edge_agg_kernel<<<(NEDGE + 3) / 4, 256, 0, stream>>>(YZ, E2S, E2D, E2M, AGG, CNT, NEDGE);
  sage_finish_kernel<<<(M2_ * NHID_ + 255) / 256, 256, 0, stream>>>(AGG, CNT, c_bl[2], YZ, M2_);
  dots_kernel<<<(M2_ + 3) / 4, 256, 0, stream>>>(AGG, p_wrel[2], p_wroot[2], T, R, M2_);
  hipMemsetAsync(SAGG, 0, M2_ * sizeof(float), stream);
  sagg_edge_kernel<<<(NEDGE + 255) / 256, 256, 0, stream>>>(T, E2S, E2D, E2M, SAGG, NEDGE);
  score_finish_kernel<<<(M2_ + 255) / 256, 256, 0, stream>>>(SAGG, R, p_brel[2], SCORE, M2_);
  hipMemsetAsync(MAP, 0xFF, M2_ * sizeof(int), stream);
  topk_kernel<64><<<G_, 256, 0, stream>>>(SCORE, K1_, K2_, SEL, OLD, MAP);
  gather_gate_kernel<<<M3_, 128, 0, stream>>>(AGG, SEL, OLD, NX);
  readout_kernel<<<G_, 128, 0, stream>>>(NX, H, K2_);

  // ---- head ----
  head_kernel<<<1, 256, 0, stream>>>(H, gpp, lin1_w, lin1_b, lin2_w, lin2_b,
                                     grade_w, grade_b, haz_w, haz_b, (float*)d_out);
}

// Round 5
// 485.208 us; speedup vs baseline: 2.4764x; 1.1453x over previous
//
#include <hip/hip_runtime.h>
#include <math.h>
#include <cfloat>

// ---------------- problem constants ----------------
#define G_    50
#define N0_   1000
#define NEDGE 200000
#define P_    10
#define FEAT_ 1036
#define NHID_ 128
#define GDIM_ 32
#define K0_   200          // ceil(0.2*1000)
#define K1_   40           // ceil(0.2*200)
#define K2_   8            // ceil(0.2*40)
#define M0_   (G_*N0_)     // 50000
#define M1_   (G_*K0_)     // 10000
#define M2_   (G_*K1_)     // 2000
#define M3_   (G_*K2_)     // 400

#define KPAD_ 1056         // 1036 padded to multiple of 32
#define MPAD0_ 50048       // 50000 -> mult of 64
#define MPAD1_ 10048       // 10000 -> mult of 64
#define MPAD2_ 2048        // 2000  -> mult of 64
#define MPAD3_ 448         // 400   -> mult of 64

typedef __attribute__((ext_vector_type(8))) short s16x8;
typedef __attribute__((ext_vector_type(4))) float f32x4;

__device__ __forceinline__ unsigned f2bf1(float f) {   // bf16 bits, RNE
  unsigned u = __float_as_uint(f);
  return (u + 0x7FFFu + ((u >> 16) & 1u)) >> 16;
}
__device__ __forceinline__ unsigned packbf(float a, float b) {
  return f2bf1(a) | (f2bf1(b) << 16);
}
__device__ __forceinline__ float bf2f(unsigned short b) {
  return __uint_as_float((unsigned)b << 16);
}

__device__ __forceinline__ void gload_lds16(const void* g, void* l) {
  __builtin_amdgcn_global_load_lds((const __attribute__((address_space(1))) void*)g,
                                   (__attribute__((address_space(3))) void*)l, 16, 0, 0);
}

// ---------------- kernels ----------------

// row-major colmax: each thread reads cols 0..11 of its rows (1 cache line/row)
__global__ void colmax_kernel(const float* __restrict__ x, int* __restrict__ scale_i) {
  int tid = threadIdx.x, wave = tid >> 6, lane = tid & 63;
  float mx[12];
#pragma unroll
  for (int j = 0; j < 12; j++) mx[j] = 0.f;
  for (int r = blockIdx.x * 256 + tid; r < M0_; r += gridDim.x * 256) {
    const float4* p = (const float4*)(x + (size_t)r * FEAT_);
    float4 a = p[0], b = p[1], c = p[2];
    mx[0] = fmaxf(mx[0], a.x); mx[1] = fmaxf(mx[1], a.y);
    mx[2] = fmaxf(mx[2], a.z); mx[3] = fmaxf(mx[3], a.w);
    mx[4] = fmaxf(mx[4], b.x); mx[5] = fmaxf(mx[5], b.y);
    mx[6] = fmaxf(mx[6], b.z); mx[7] = fmaxf(mx[7], b.w);
    mx[8] = fmaxf(mx[8], c.x); mx[9] = fmaxf(mx[9], c.y);
    mx[10] = fmaxf(mx[10], c.z); mx[11] = fmaxf(mx[11], c.w);
  }
#pragma unroll
  for (int off = 32; off > 0; off >>= 1)
#pragma unroll
    for (int j = 0; j < 12; j++) mx[j] = fmaxf(mx[j], __shfl_down(mx[j], off));
  __shared__ float red[4][12];
  if (lane == 0)
#pragma unroll
    for (int j = 0; j < 12; j++) red[wave][j] = mx[j];
  __syncthreads();
  if (tid < 12) {
    float m = fmaxf(fmaxf(red[0][tid], red[1][tid]), fmaxf(red[2][tid], red[3][tid]));
    atomicMax(scale_i + tid, __float_as_int(m));
  }
}

// WT0[c][j] = bf16( scaled W[j][c] ), c in [0,256), j in [0,KPAD_) (pad j>=1036 -> 0)
__global__ void build_wt0_kernel(const float* __restrict__ wl, const float* __restrict__ wr,
                                 const int* __restrict__ scale_i, unsigned short* __restrict__ WT) {
  int idx = blockIdx.x * blockDim.x + threadIdx.x;
  if (idx >= 256 * KPAD_) return;
  int c = idx / KPAD_, j = idx % KPAD_;
  float w = 0.f;
  if (j < FEAT_) {
    w = (c < NHID_) ? wl[j * NHID_ + c] : wr[j * NHID_ + (c - NHID_)];
    if (j < 12) w *= 1.0f / __int_as_float(scale_i[j]);
  }
  WT[idx] = (unsigned short)f2bf1(w);
}

// WT12[c][j] = bf16(W[j][c]), c in [0,256), j in [0,128)
__global__ void build_wt12_kernel(const float* __restrict__ wl, const float* __restrict__ wr,
                                  unsigned short* __restrict__ WT) {
  int idx = blockIdx.x * blockDim.x + threadIdx.x;
  if (idx >= 256 * 128) return;
  int c = idx >> 7, j = idx & 127;
  float w = (c < NHID_) ? wl[j * NHID_ + c] : wr[j * NHID_ + (c - NHID_)];
  WT[idx] = (unsigned short)f2bf1(w);
}

// C[M x 256] = A @ WT^T.  WT [256][ldb] bf16 row-major.
// 64x256 tile; 4 waves (each 64 rows x 64 cols via 4x4 16x16x32 frags).
// AF32: A f32 [.,lda], converted in-regs; else A bf16 [.,lda=ldb].
template <bool AF32>
__global__ __launch_bounds__(256) void mfma_gemm_kernel(const float* __restrict__ Af,
                                                        const unsigned short* __restrict__ Ab,
                                                        const unsigned short* __restrict__ WT,
                                                        float* __restrict__ C, int M,
                                                        int lda, int ldb, int kvalid, int ksteps) {
  __shared__ unsigned short As[64 * 32];    // [row][k]
  __shared__ unsigned short Bs[256 * 32];   // [col][k]
  const int bm = blockIdx.x * 64;
  const int tid = threadIdx.x, wave = tid >> 6, lane = tid & 63;
  const int lhi = lane >> 4, llo = lane & 15;
  const int arow = tid >> 2, aseg = tid & 3;   // A staging: 8 k-elems per thread
  f32x4 acc[4][4] = {};

  for (int st = 0; st < ksteps; st++) {
    const int k0 = st * 32;
    // ---- stage B: 256x32 bf16 = 1024 16B chunks, 4 per thread via global_load_lds
#pragma unroll
    for (int it = 0; it < 4; it++) {
      int c = it * 256 + wave * 64 + lane;
      int row = c >> 2, cb = c & 3;
      gload_lds16(WT + (size_t)row * ldb + k0 + cb * 8, Bs + (size_t)(it * 256 + wave * 64) * 8);
    }
    // ---- stage A: 64 rows x 32 k
    if (AF32) {
      int gr = bm + arow;
      int gk = k0 + aseg * 8;
      float f[8];
      if (gr < M && gk + 8 <= kvalid) {
        const float4* ap = (const float4*)(Af + (size_t)gr * lda + gk);
        float4 v0 = ap[0], v1 = ap[1];
        f[0] = v0.x; f[1] = v0.y; f[2] = v0.z; f[3] = v0.w;
        f[4] = v1.x; f[5] = v1.y; f[6] = v1.z; f[7] = v1.w;
      } else {
        const float* ap = Af + (size_t)gr * lda + gk;
#pragma unroll
        for (int j = 0; j < 8; j++)
          f[j] = (gr < M && gk + j < kvalid) ? ap[j] : 0.f;
      }
      uint4 p;
      p.x = packbf(f[0], f[1]); p.y = packbf(f[2], f[3]);
      p.z = packbf(f[4], f[5]); p.w = packbf(f[6], f[7]);
      *(uint4*)&As[arow * 32 + aseg * 8] = p;
    } else {
      uint4 v = *(const uint4*)(Ab + (size_t)(bm + arow) * lda + k0 + aseg * 8);
      *(uint4*)&As[arow * 32 + aseg * 8] = v;
    }
    __syncthreads();   // drains vmcnt (gload_lds) + lgkmcnt (ds_write)

    s16x8 a[4], b[4];
#pragma unroll
    for (int mt = 0; mt < 4; mt++)
      a[mt] = *(const s16x8*)&As[(mt * 16 + llo) * 32 + lhi * 8];
#pragma unroll
    for (int nt = 0; nt < 4; nt++)
      b[nt] = *(const s16x8*)&Bs[(wave * 64 + nt * 16 + llo) * 32 + lhi * 8];
#pragma unroll
    for (int mt = 0; mt < 4; mt++)
#pragma unroll
      for (int nt = 0; nt < 4; nt++)
        acc[mt][nt] = __builtin_amdgcn_mfma_f32_16x16x32_bf16(a[mt], b[nt], acc[mt][nt], 0, 0, 0);
    __syncthreads();
  }

  // C/D layout: col = lane&15, row = (lane>>4)*4 + q
#pragma unroll
  for (int mt = 0; mt < 4; mt++) {
#pragma unroll
    for (int q = 0; q < 4; q++) {
      int row = bm + mt * 16 + lhi * 4 + q;
      if (row < M) {
#pragma unroll
        for (int nt = 0; nt < 4; nt++)
          C[(size_t)row * 256 + wave * 64 + nt * 16 + llo] = acc[mt][nt][q];
      }
    }
  }
}

// agg[dst] += Y[src]*m (128 dims; Y row stride 256), cnt[dst] += m.  One wave per edge.
__global__ void edge_agg_kernel(const float* __restrict__ Y,
                                const int* __restrict__ src, const int* __restrict__ dst,
                                const float* __restrict__ m,
                                float* __restrict__ agg, float* __restrict__ cnt, int nEdge) {
  int wid = threadIdx.x >> 6, lane = threadIdx.x & 63;
  int e = blockIdx.x * 4 + wid;
  if (e >= nEdge) return;
  float me = m ? m[e] : 1.0f;
  if (me == 0.f) return;
  int s = src[e], d = dst[e];
  float v0 = Y[(size_t)s * 256 + lane] * me;
  float v1 = Y[(size_t)s * 256 + 64 + lane] * me;
  atomicAdd(agg + (size_t)d * 128 + lane, v0);
  atomicAdd(agg + (size_t)d * 128 + 64 + lane, v1);
  if (lane == 0) atomicAdd(cnt + d, me);
}

// fused: x = relu(agg/max(cnt,1)+bl+Z) in-place; T = x·wrel; R = x·wroot. One wave/row.
__global__ void sage_dots_kernel(float* __restrict__ aggx, const float* __restrict__ cnt,
                                 const float* __restrict__ bl, const float* __restrict__ YZ,
                                 const float* __restrict__ wrel, const float* __restrict__ wroot,
                                 float* __restrict__ T, float* __restrict__ R, int M) {
  int wid = threadIdx.x >> 6, lane = threadIdx.x & 63;
  int i = blockIdx.x * 4 + wid;
  if (i >= M) return;
  float ic = 1.f / fmaxf(cnt[i], 1.f);
  float v0 = aggx[(size_t)i * 128 + lane] * ic + bl[lane] + YZ[(size_t)i * 256 + 128 + lane];
  float v1 = aggx[(size_t)i * 128 + 64 + lane] * ic + bl[64 + lane] + YZ[(size_t)i * 256 + 192 + lane];
  v0 = fmaxf(v0, 0.f); v1 = fmaxf(v1, 0.f);
  aggx[(size_t)i * 128 + lane] = v0;
  aggx[(size_t)i * 128 + 64 + lane] = v1;
  float t = v0 * wrel[lane] + v1 * wrel[64 + lane];
  float r = v0 * wroot[lane] + v1 * wroot[64 + lane];
#pragma unroll
  for (int off = 32; off > 0; off >>= 1) {
    t += __shfl_down(t, off);
    r += __shfl_down(r, off);
  }
  if (lane == 0) { T[i] = t; R[i] = r; }
}

__global__ void sagg_edge_kernel(const float* __restrict__ T, const int* __restrict__ src,
                                 const int* __restrict__ dst, const float* __restrict__ m,
                                 float* __restrict__ sagg, int nEdge) {
  int e = blockIdx.x * blockDim.x + threadIdx.x;
  if (e >= nEdge) return;
  float me = m ? m[e] : 1.0f;
  if (me == 0.f) return;
  atomicAdd(sagg + dst[e], T[src[e]] * me);
}

// one block per graph: score = sagg + R + brel; bitonic sort desc; emit top-k set
template <int NP>
__global__ void topk_kernel(const float* __restrict__ sagg, const float* __restrict__ R,
                            const float* __restrict__ brel, int n, int k,
                            float* __restrict__ sel, int* __restrict__ oldidx,
                            int* __restrict__ mapping) {
  __shared__ float val[NP];
  __shared__ int ind[NP];
  int g = blockIdx.x;
  float b0 = brel[0];
  for (int t = threadIdx.x; t < NP; t += blockDim.x) {
    val[t] = (t < n) ? (sagg[g * n + t] + R[g * n + t] + b0) : -FLT_MAX;
    ind[t] = t;
  }
  __syncthreads();
  for (int kk = 2; kk <= NP; kk <<= 1) {
    for (int j = kk >> 1; j > 0; j >>= 1) {
      for (int i = threadIdx.x; i < NP; i += blockDim.x) {
        int ixj = i ^ j;
        if (ixj > i) {
          bool desc = ((i & kk) == 0);
          float vi = val[i], vj = val[ixj];
          if (desc ? (vi < vj) : (vi > vj)) {
            val[i] = vj; val[ixj] = vi;
            int tmp = ind[i]; ind[i] = ind[ixj]; ind[ixj] = tmp;
          }
        }
      }
      __syncthreads();
    }
  }
  for (int t = threadIdx.x; t < k; t += blockDim.x) {
    int gid = g * k + t;
    sel[gid] = val[t];
    int node = ind[t];
    oldidx[gid] = g * n + node;
    mapping[g * n + node] = gid;
  }
}

// NXB[v] = bf16( X[oldidx[v]] * tanh(sel[v]) ) for v<Mnext, zeros for pad rows
__global__ void gather_gate_kernel(const float* __restrict__ X, const float* __restrict__ sel,
                                   const int* __restrict__ oldidx,
                                   unsigned short* __restrict__ NXB, int Mnext) {
  int v = blockIdx.x, c = threadIdx.x;  // 128 threads
  if (v < Mnext) {
    float gate = tanhf(sel[v]);
    NXB[(size_t)v * 128 + c] = (unsigned short)f2bf1(X[(size_t)oldidx[v] * 128 + c] * gate);
  } else {
    NXB[(size_t)v * 128 + c] = 0;
  }
}

__global__ void edge_remap_kernel(const int* __restrict__ src, const int* __restrict__ dst,
                                  const float* __restrict__ m, const int* __restrict__ mapping,
                                  int* __restrict__ nsrc, int* __restrict__ ndst,
                                  float* __restrict__ nm, int nEdge) {
  int e = blockIdx.x * blockDim.x + threadIdx.x;
  if (e >= nEdge) return;
  int ns = mapping[src[e]], nd = mapping[dst[e]];
  float me = m ? m[e] : 1.0f;
  nm[e] = (ns >= 0 && nd >= 0) ? me : 0.f;
  nsrc[e] = max(ns, 0);
  ndst[e] = max(nd, 0);
}

// H[g, 0:128] += max over k rows; H[g, 128:256] += mean over k rows (NXB bf16)
__global__ void readout_kernel(const unsigned short* __restrict__ NXB, float* __restrict__ H, int k) {
  int g = blockIdx.x, c = threadIdx.x;  // 128 threads
  float mx = -FLT_MAX, sm = 0.f;
  for (int j = 0; j < k; j++) {
    float v = bf2f(NXB[((size_t)g * k + j) * 128 + c]);
    mx = fmaxf(mx, v);
    sm += v;
  }
  H[g * 256 + c] += mx;
  H[g * 256 + 128 + c] += sm / (float)k;
}

__global__ void head_kernel(const float* __restrict__ H, const int* __restrict__ gpp,
                            const float* __restrict__ lin1_w, const float* __restrict__ lin1_b,
                            const float* __restrict__ lin2_w, const float* __restrict__ lin2_b,
                            const float* __restrict__ grade_w, const float* __restrict__ grade_b,
                            const float* __restrict__ haz_w, const float* __restrict__ haz_b,
                            float* __restrict__ out) {
  __shared__ float pooled[P_][256];
  __shared__ float h1[P_][NHID_];
  __shared__ float feats[P_][GDIM_];
  __shared__ int off[P_ + 1];
  int tid = threadIdx.x;
  if (tid == 0) {
    off[0] = 0;
    for (int p = 0; p < P_; p++) off[p + 1] = min(off[p] + gpp[p], G_);
  }
  __syncthreads();
  for (int idx = tid; idx < P_ * 256; idx += blockDim.x) {
    int p = idx >> 8, c = idx & 255;
    int a = off[p], b = (p == P_ - 1) ? G_ : off[p + 1];
    float s = 0.f;
    for (int gq = a; gq < b; gq++) s += H[gq * 256 + c];
    pooled[p][c] = s / (float)gpp[p];
  }
  __syncthreads();
  for (int idx = tid; idx < P_ * NHID_; idx += blockDim.x) {
    int p = idx >> 7, o = idx & 127;
    float acc = lin1_b[o];
    for (int c = 0; c < 256; c++) acc += pooled[p][c] * lin1_w[c * NHID_ + o];
    h1[p][o] = fmaxf(acc, 0.f);
  }
  __syncthreads();
  for (int idx = tid; idx < P_ * GDIM_; idx += blockDim.x) {
    int p = idx / GDIM_, o = idx % GDIM_;
    float acc = lin2_b[o];
    for (int c = 0; c < NHID_; c++) acc += h1[p][c] * lin2_w[c * GDIM_ + o];
    float f = fmaxf(acc, 0.f);
    feats[p][o] = f;
    out[p * GDIM_ + o] = f;
  }
  __syncthreads();
  if (tid < P_) {
    int p = tid;
    float l[3];
    float mx = -FLT_MAX;
    for (int j = 0; j < 3; j++) {
      float acc = grade_b[j];
      for (int c = 0; c < GDIM_; c++) acc += feats[p][c] * grade_w[c * 3 + j];
      l[j] = acc;
      mx = fmaxf(mx, acc);
    }
    float se = 0.f;
    for (int j = 0; j < 3; j++) se += expf(l[j] - mx);
    float lse = mx + logf(se);
    for (int j = 0; j < 3; j++) out[P_ * GDIM_ + p * 3 + j] = l[j] - lse;
    float z = haz_b[0];
    for (int c = 0; c < GDIM_; c++) z += feats[p][c] * haz_w[c];
    out[P_ * GDIM_ + P_ * 3 + p] = 6.f / (1.f + expf(-z)) - 3.f;
  }
}

// ---------------- launch ----------------
extern "C" void kernel_launch(void* const* d_in, const int* in_sizes, int n_in,
                              void* d_out, int out_size, void* d_ws, size_t ws_size,
                              hipStream_t stream) {
  (void)in_sizes; (void)n_in; (void)out_size; (void)ws_size;
  const float* x  = (const float*)d_in[0];
  const int* ei   = (const int*)d_in[1];
  const int* gpp  = (const int*)d_in[2];
  const float* c_wl[3]    = {(const float*)d_in[3],  (const float*)d_in[9],  (const float*)d_in[15]};
  const float* c_bl[3]    = {(const float*)d_in[4],  (const float*)d_in[10], (const float*)d_in[16]};
  const float* c_wr[3]    = {(const float*)d_in[5],  (const float*)d_in[11], (const float*)d_in[17]};
  const float* p_wrel[3]  = {(const float*)d_in[6],  (const float*)d_in[12], (const float*)d_in[18]};
  const float* p_brel[3]  = {(const float*)d_in[7],  (const float*)d_in[13], (const float*)d_in[19]};
  const float* p_wroot[3] = {(const float*)d_in[8],  (const float*)d_in[14], (const float*)d_in[20]};
  const float* lin1_w = (const float*)d_in[21];
  const float* lin1_b = (const float*)d_in[22];
  const float* lin2_w = (const float*)d_in[23];
  const float* lin2_b = (const float*)d_in[24];
  const float* grade_w = (const float*)d_in[25];
  const float* grade_b = (const float*)d_in[26];
  const float* haz_w = (const float*)d_in[27];
  const float* haz_b = (const float*)d_in[28];

  // ---- workspace layout (256B-aligned blocks), ~85 MB ----
  char* wsb = (char*)d_ws;
  size_t off = 0;
  auto alloc = [&](size_t bytes) -> void* {
    void* p = wsb + off;
    off += (bytes + 255) & ~(size_t)255;
    return p;
  };
  int*            SCALE = (int*)alloc(64 * 4);
  unsigned short* WT0   = (unsigned short*)alloc((size_t)256 * KPAD_ * 2);
  unsigned short* WT12  = (unsigned short*)alloc((size_t)256 * 128 * 2);
  float*          YZ    = (float*)alloc((size_t)M0_ * 256 * 4);
  float*          H     = (float*)alloc((size_t)G_ * 256 * 4);
  float* AGG   = (float*)alloc((size_t)M0_ * 128 * 4);     // zone start
  float* CNT   = (float*)alloc((size_t)M0_ * 4);
  float* SAGG  = (float*)alloc((size_t)M0_ * 4);           // zone end
  size_t zoneBytes = (size_t)((char*)(SAGG + M0_) - (char*)AGG);
  unsigned short* NXB = (unsigned short*)alloc((size_t)MPAD1_ * 128 * 2);
  float* T     = (float*)alloc((size_t)M0_ * 4);
  float* R     = (float*)alloc((size_t)M0_ * 4);
  float* SEL   = (float*)alloc((size_t)M1_ * 4);
  int*   OLD   = (int*)alloc((size_t)M1_ * 4);
  int*   MAP   = (int*)alloc((size_t)M0_ * 4);
  int*   E1S   = (int*)alloc((size_t)NEDGE * 4);
  int*   E1D   = (int*)alloc((size_t)NEDGE * 4);
  float* E1M   = (float*)alloc((size_t)NEDGE * 4);
  int*   E2S   = (int*)alloc((size_t)NEDGE * 4);
  int*   E2D   = (int*)alloc((size_t)NEDGE * 4);
  float* E2M   = (float*)alloc((size_t)NEDGE * 4);

  const int* src0 = ei;
  const int* dst0 = ei + NEDGE;

  hipMemsetAsync(H, 0, G_ * 256 * sizeof(float), stream);
  hipMemsetAsync(SCALE, 0, 12 * sizeof(int), stream);

  // ---- layer 0 ----
  colmax_kernel<<<128, 256, 0, stream>>>(x, SCALE);
  build_wt0_kernel<<<(256 * KPAD_ + 255) / 256, 256, 0, stream>>>(c_wl[0], c_wr[0], SCALE, WT0);
  hipMemsetAsync(AGG, 0, zoneBytes, stream);
  hipMemsetAsync(MAP, 0xFF, M0_ * sizeof(int), stream);
  mfma_gemm_kernel<true><<<MPAD0_ / 64, 256, 0, stream>>>(x, nullptr, WT0, YZ, M0_, FEAT_, KPAD_, FEAT_, KPAD_ / 32);
  edge_agg_kernel<<<(NEDGE + 3) / 4, 256, 0, stream>>>(YZ, src0, dst0, nullptr, AGG, CNT, NEDGE);
  sage_dots_kernel<<<(M0_ + 3) / 4, 256, 0, stream>>>(AGG, CNT, c_bl[0], YZ, p_wrel[0], p_wroot[0], T, R, M0_);
  sagg_edge_kernel<<<(NEDGE + 255) / 256, 256, 0, stream>>>(T, src0, dst0, nullptr, SAGG, NEDGE);
  topk_kernel<1024><<<G_, 512, 0, stream>>>(SAGG, R, p_brel[0], N0_, K0_, SEL, OLD, MAP);
  gather_gate_kernel<<<MPAD1_, 128, 0, stream>>>(AGG, SEL, OLD, NXB, M1_);
  edge_remap_kernel<<<(NEDGE + 255) / 256, 256, 0, stream>>>(src0, dst0, nullptr, MAP, E1S, E1D, E1M, NEDGE);
  readout_kernel<<<G_, 128, 0, stream>>>(NXB, H, K0_);

  // ---- layer 1 ----
  build_wt12_kernel<<<(256 * 128 + 255) / 256, 256, 0, stream>>>(c_wl[1], c_wr[1], WT12);
  hipMemsetAsync(AGG, 0, zoneBytes, stream);
  hipMemsetAsync(MAP, 0xFF, M0_ * sizeof(int), stream);
  mfma_gemm_kernel<false><<<MPAD1_ / 64, 256, 0, stream>>>(nullptr, NXB, WT12, YZ, MPAD1_, 128, 128, 128, 4);
  edge_agg_kernel<<<(NEDGE + 3) / 4, 256, 0, stream>>>(YZ, E1S, E1D, E1M, AGG, CNT, NEDGE);
  sage_dots_kernel<<<(M1_ + 3) / 4, 256, 0, stream>>>(AGG, CNT, c_bl[1], YZ, p_wrel[1], p_wroot[1], T, R, M1_);
  sagg_edge_kernel<<<(NEDGE + 255) / 256, 256, 0, stream>>>(T, E1S, E1D, E1M, SAGG, NEDGE);
  topk_kernel<256><<<G_, 256, 0, stream>>>(SAGG, R, p_brel[1], K0_, K1_, SEL, OLD, MAP);
  gather_gate_kernel<<<MPAD2_, 128, 0, stream>>>(AGG, SEL, OLD, NXB, M2_);
  edge_remap_kernel<<<(NEDGE + 255) / 256, 256, 0, stream>>>(E1S, E1D, E1M, MAP, E2S, E2D, E2M, NEDGE);
  readout_kernel<<<G_, 128, 0, stream>>>(NXB, H, K1_);

  // ---- layer 2 ----
  build_wt12_kernel<<<(256 * 128 + 255) / 256, 256, 0, stream>>>(c_wl[2], c_wr[2], WT12);
  hipMemsetAsync(AGG, 0, zoneBytes, stream);
  hipMemsetAsync(MAP, 0xFF, M0_ * sizeof(int), stream);
  mfma_gemm_kernel<false><<<MPAD2_ / 64, 256, 0, stream>>>(nullptr, NXB, WT12, YZ, MPAD2_, 128, 128, 128, 4);
  edge_agg_kernel<<<(NEDGE + 3) / 4, 256, 0, stream>>>(YZ, E2S, E2D, E2M, AGG, CNT, NEDGE);
  sage_dots_kernel<<<(M2_ + 3) / 4, 256, 0, stream>>>(AGG, CNT, c_bl[2], YZ, p_wrel[2], p_wroot[2], T, R, M2_);
  sagg_edge_kernel<<<(NEDGE + 255) / 256, 256, 0, stream>>>(T, E2S, E2D, E2M, SAGG, NEDGE);
  topk_kernel<64><<<G_, 64, 0, stream>>>(SAGG, R, p_brel[2], K1_, K2_, SEL, OLD, MAP);
  gather_gate_kernel<<<MPAD3_, 128, 0, stream>>>(AGG, SEL, OLD, NXB, M3_);
  readout_kernel<<<G_, 128, 0, stream>>>(NXB, H, K2_);

  // ---- head ----
  head_kernel<<<1, 256, 0, stream>>>(H, gpp, lin1_w, lin1_b, lin2_w, lin2_b,
                                     grade_w, grade_b, haz_w, haz_b, (float*)d_out);
}